// Round 1
// baseline (195.290 us; speedup 1.0000x reference)
//
#include <hip/hip_runtime.h>

#ifndef NCE_N
#define NCE_N 32768
#endif

static constexpr float INV_T = 1.0f / 0.07f;
static constexpr float EPS_F = 1e-12f;

__device__ __forceinline__ void acc_elem(float s, float l, float& num, float& den) {
    // sigmoid
    float sig = 1.0f / (1.0f + __expf(-s));
    float e = __expf(sig * INV_T);
    den += e;
    num = fmaf(e, l, num);
}

__global__ __launch_bounds__(256) void nce_row_kernel(
    const float* __restrict__ scores,
    const float* __restrict__ labels,
    float* __restrict__ row_loss,
    int N)
{
    const int row = blockIdx.x;
    const long long base = (long long)row * (long long)N;
    const float4* __restrict__ s4 = reinterpret_cast<const float4*>(scores + base);
    const float4* __restrict__ l4 = reinterpret_cast<const float4*>(labels + base);
    const int n4 = N >> 2;  // 8192 float4 per row

    float num = 0.0f, den = 0.0f;
    for (int i = threadIdx.x; i < n4; i += 256) {
        float4 s = s4[i];
        float4 l = l4[i];
        acc_elem(s.x, l.x, num, den);
        acc_elem(s.y, l.y, num, den);
        acc_elem(s.z, l.z, num, den);
        acc_elem(s.w, l.w, num, den);
    }

    // wave (64-lane) butterfly reduce
    #pragma unroll
    for (int off = 32; off > 0; off >>= 1) {
        num += __shfl_down(num, off, 64);
        den += __shfl_down(den, off, 64);
    }

    __shared__ float s_num[4];
    __shared__ float s_den[4];
    const int lane = threadIdx.x & 63;
    const int wave = threadIdx.x >> 6;
    if (lane == 0) { s_num[wave] = num; s_den[wave] = den; }
    __syncthreads();
    if (threadIdx.x == 0) {
        float n = s_num[0] + s_num[1] + s_num[2] + s_num[3];
        float d = s_den[0] + s_den[1] + s_den[2] + s_den[3];
        row_loss[row] = -logf(n / (d + EPS_F) + EPS_F);
    }
}

__global__ __launch_bounds__(256) void nce_mean_kernel(
    const float* __restrict__ row_loss,
    float* __restrict__ out,
    int B)
{
    float s = 0.0f;
    for (int i = threadIdx.x; i < B; i += 256) s += row_loss[i];

    #pragma unroll
    for (int off = 32; off > 0; off >>= 1)
        s += __shfl_down(s, off, 64);

    __shared__ float s_part[4];
    const int lane = threadIdx.x & 63;
    const int wave = threadIdx.x >> 6;
    if (lane == 0) s_part[wave] = s;
    __syncthreads();
    if (threadIdx.x == 0) {
        float t = s_part[0] + s_part[1] + s_part[2] + s_part[3];
        out[0] = t / (float)B;
    }
}

extern "C" void kernel_launch(void* const* d_in, const int* in_sizes, int n_in,
                              void* d_out, int out_size, void* d_ws, size_t ws_size,
                              hipStream_t stream) {
    const float* scores = (const float*)d_in[0];
    const float* labels = (const float*)d_in[1];
    float* out = (float*)d_out;

    const int N = NCE_N;
    const int B = in_sizes[0] / N;  // 4096

    float* row_loss = (float*)d_ws;  // B floats of scratch

    nce_row_kernel<<<B, 256, 0, stream>>>(scores, labels, row_loss, N);
    nce_mean_kernel<<<1, 256, 0, stream>>>(row_loss, out, B);
}

// Round 3
// 168.770 us; speedup vs baseline: 1.1571x; 1.1571x over previous
//
#include <hip/hip_runtime.h>

#ifndef NCE_N
#define NCE_N 32768
#endif

static constexpr float INV_T = 1.0f / 0.07f;
static constexpr float EPS_F = 1e-12f;

typedef float f32x4 __attribute__((ext_vector_type(4)));

__device__ __forceinline__ void acc_elem(float s, float l, float& num, float& den) {
    float sig = 1.0f / (1.0f + __expf(-s));
    float e = __expf(sig * INV_T);
    den += e;
    num = fmaf(e, l, num);
}

__device__ __forceinline__ void acc4(const f32x4& s, const f32x4& l, float& num, float& den) {
    acc_elem(s.x, l.x, num, den);
    acc_elem(s.y, l.y, num, den);
    acc_elem(s.z, l.z, num, den);
    acc_elem(s.w, l.w, num, den);
}

__global__ __launch_bounds__(256) void nce_row_kernel(
    const float* __restrict__ scores,
    const float* __restrict__ labels,
    float* __restrict__ row_loss,
    int N)
{
    const int row = blockIdx.x;
    const long long base = (long long)row * (long long)N;
    const f32x4* __restrict__ s4 = reinterpret_cast<const f32x4*>(scores + base);
    const f32x4* __restrict__ l4 = reinterpret_cast<const f32x4*>(labels + base);
    const int n4 = N >> 2;  // 8192 float4 per row (N = 32768)

    float num = 0.0f, den = 0.0f;

    // 2x-unrolled streaming loop: 4 nontemporal dwordx4 loads in flight/iter.
    // n4 = 8192 = 16 * 512, so the unrolled pair (i, i+256) always fits.
    int i = threadIdx.x;
    for (; i + 256 < n4; i += 512) {
        f32x4 s0 = __builtin_nontemporal_load(&s4[i]);
        f32x4 s1 = __builtin_nontemporal_load(&s4[i + 256]);
        f32x4 l0 = __builtin_nontemporal_load(&l4[i]);
        f32x4 l1 = __builtin_nontemporal_load(&l4[i + 256]);
        acc4(s0, l0, num, den);
        acc4(s1, l1, num, den);
    }
    for (; i < n4; i += 256) {  // tail (not taken for N=32768)
        f32x4 s0 = __builtin_nontemporal_load(&s4[i]);
        f32x4 l0 = __builtin_nontemporal_load(&l4[i]);
        acc4(s0, l0, num, den);
    }

    #pragma unroll
    for (int off = 32; off > 0; off >>= 1) {
        num += __shfl_down(num, off, 64);
        den += __shfl_down(den, off, 64);
    }

    __shared__ float s_num[4];
    __shared__ float s_den[4];
    const int lane = threadIdx.x & 63;
    const int wave = threadIdx.x >> 6;
    if (lane == 0) { s_num[wave] = num; s_den[wave] = den; }
    __syncthreads();
    if (threadIdx.x == 0) {
        float n = s_num[0] + s_num[1] + s_num[2] + s_num[3];
        float d = s_den[0] + s_den[1] + s_den[2] + s_den[3];
        row_loss[row] = -logf(n / (d + EPS_F) + EPS_F);
    }
}

__global__ __launch_bounds__(256) void nce_mean_kernel(
    const float* __restrict__ row_loss,
    float* __restrict__ out,
    int B)
{
    float s = 0.0f;
    for (int i = threadIdx.x; i < B; i += 256) s += row_loss[i];

    #pragma unroll
    for (int off = 32; off > 0; off >>= 1)
        s += __shfl_down(s, off, 64);

    __shared__ float s_part[4];
    const int lane = threadIdx.x & 63;
    const int wave = threadIdx.x >> 6;
    if (lane == 0) s_part[wave] = s;
    __syncthreads();
    if (threadIdx.x == 0) {
        float t = s_part[0] + s_part[1] + s_part[2] + s_part[3];
        out[0] = t / (float)B;
    }
}

extern "C" void kernel_launch(void* const* d_in, const int* in_sizes, int n_in,
                              void* d_out, int out_size, void* d_ws, size_t ws_size,
                              hipStream_t stream) {
    const float* scores = (const float*)d_in[0];
    const float* labels = (const float*)d_in[1];
    float* out = (float*)d_out;

    const int N = NCE_N;
    const int B = in_sizes[0] / N;  // 4096

    float* row_loss = (float*)d_ws;  // B floats of scratch

    nce_row_kernel<<<B, 256, 0, stream>>>(scores, labels, row_loss, N);
    nce_mean_kernel<<<1, 256, 0, stream>>>(row_loss, out, B);
}